// Round 2
// baseline (342.734 us; speedup 1.0000x reference)
//
#include <hip/hip_runtime.h>
#include <math.h>

typedef __attribute__((ext_vector_type(4))) float f32x4;
typedef __attribute__((ext_vector_type(8))) short bf16x8;
typedef __attribute__((ext_vector_type(2))) unsigned int uint2v;
typedef __attribute__((ext_vector_type(4))) unsigned int uint4v;

#define LOG2E 1.4426950408889634f
#define MT 32            // m-tile
#define NIT 128          // 4096 / MT

static __device__ __forceinline__ unsigned short f2bf(float f) {
  union { float f; unsigned int i; } u; u.f = f;
  unsigned int r = u.i + 0x7fffu + ((u.i >> 16) & 1u);   // RNE
  return (unsigned short)(r >> 16);
}

typedef __attribute__((address_space(3))) unsigned int lds_u32;
typedef __attribute__((address_space(1))) unsigned int g_u32;

// async global->LDS, 16B per lane; LDS dest = wave-uniform base + lane*16
static __device__ __forceinline__ void gload_lds16(const unsigned short* g,
                                                   const unsigned short* l) {
  __builtin_amdgcn_global_load_lds(
      (const g_u32*)(unsigned long long)g,
      (lds_u32*)(unsigned int)(unsigned long long)l, 16, 0, 0);
}

// ---------------- kernel 0: transpose first-layer weights [32][256] -> [256][32]
__global__ __launch_bounds__(256) void k_wprep(const float* __restrict__ w1a,
                                               const float* __restrict__ w2a,
                                               float* __restrict__ w1aT,
                                               float* __restrict__ w2aT) {
  int i = blockIdx.x * 256 + threadIdx.x;
  if (i < 32 * 256) {
    int o = i >> 8, c = i & 255;
    w1aT[c * 32 + o] = w1a[i];
    w2aT[c * 32 + o] = w2a[i];
  }
}

// ---------------- kernel 0b: F (fp32) -> Fbf (bf16), vectorized
__global__ __launch_bounds__(256) void k_cvt(const float* __restrict__ F,
                                             unsigned short* __restrict__ Fbf) {
  size_t i = ((size_t)blockIdx.x * 256 + threadIdx.x) * 8;
  f32x4 a = *(const f32x4*)(F + i);
  f32x4 b = *(const f32x4*)(F + i + 4);
  unsigned int u0 = (unsigned int)f2bf(a[0]) | ((unsigned int)f2bf(a[1]) << 16);
  unsigned int u1 = (unsigned int)f2bf(a[2]) | ((unsigned int)f2bf(a[3]) << 16);
  unsigned int u2 = (unsigned int)f2bf(b[0]) | ((unsigned int)f2bf(b[1]) << 16);
  unsigned int u3 = (unsigned int)f2bf(b[2]) | ((unsigned int)f2bf(b[3]) << 16);
  uint4v v = {u0, u1, u2, u3};
  *(uint4v*)(Fbf + i) = v;
}

// ---------------- kernel 1: q/k projections, software-pipelined loads
__global__ __launch_bounds__(128) void k_qk(
    const float* __restrict__ F,
    const float* __restrict__ w1aT, const float* __restrict__ b1a,
    const float* __restrict__ w1b,  const float* __restrict__ b1b,
    const float* __restrict__ w2aT, const float* __restrict__ b2a,
    const float* __restrict__ w2b,  const float* __restrict__ b2b,
    unsigned short* __restrict__ qT,
    unsigned short* __restrict__ kT) {
  const int p = blockIdx.x & 1;
  const int nflat = (blockIdx.x >> 1) * 128 + threadIdx.x;   // b*4096+n
  const int b = nflat >> 12, n = nflat & 4095;
  const float* wA = p ? w2aT : w1aT;
  const float* bA = p ? b2a : b1a;
  const float* wB = p ? w2b : w1b;
  const float* bB = p ? b2b : b1b;
  const float* Fp = F + ((size_t)b * 256) * 4096 + n;

  float h[32];
#pragma unroll
  for (int o = 0; o < 32; ++o) h[o] = 0.f;

  float fa[8], fb[8];
#pragma unroll
  for (int j = 0; j < 8; ++j) fa[j] = Fp[(size_t)j * 4096];

  for (int cc = 0; cc < 256; cc += 16) {
#pragma unroll
    for (int j = 0; j < 8; ++j) fb[j] = Fp[(size_t)(cc + 8 + j) * 4096];
#pragma unroll
    for (int j = 0; j < 8; ++j)
#pragma unroll
      for (int o = 0; o < 32; ++o) h[o] += wA[(cc + j) * 32 + o] * fa[j];
    if (cc + 16 < 256) {
#pragma unroll
      for (int j = 0; j < 8; ++j) fa[j] = Fp[(size_t)(cc + 16 + j) * 4096];
    }
#pragma unroll
    for (int j = 0; j < 8; ++j)
#pragma unroll
      for (int o = 0; o < 32; ++o) h[o] += wA[(cc + 8 + j) * 32 + o] * fb[j];
  }
#pragma unroll
  for (int o = 0; o < 32; ++o) h[o] = fmaxf(h[o] + bA[o], 0.f);

  unsigned int pack[16];
#pragma unroll
  for (int o2 = 0; o2 < 32; o2 += 2) {
    float s0 = bB[o2], s1 = bB[o2 + 1];
#pragma unroll
    for (int o = 0; o < 32; ++o) {
      s0 += wB[o2 * 32 + o] * h[o];
      s1 += wB[(o2 + 1) * 32 + o] * h[o];
    }
    if (p == 0) { s0 *= LOG2E; s1 *= LOG2E; }   // q in exp2 domain
    pack[o2 >> 1] = (unsigned int)f2bf(s0) | ((unsigned int)f2bf(s1) << 16);
  }
  unsigned short* dst = (p ? kT : qT) + (size_t)nflat * 32;
  uint4v* d4 = (uint4v*)dst;
#pragma unroll
  for (int i = 0; i < 4; ++i) {
    uint4v v = {pack[4 * i], pack[4 * i + 1], pack[4 * i + 2], pack[4 * i + 3]};
    d4[i] = v;
  }
}

// ---------------- kernel 2: flash attention + residual
// Block: 4 waves, 64 q-rows (16/wave for QK^T+softmax); PV is c-split: wave w
// owns channels [64w, 64w+64). V staged via global_load_lds, triple-buffered,
// XOR chunk-swizzle (both sides). P shared via double-buffered swizzled Pb.
// One barrier per m-tile.
__global__ __launch_bounds__(256, 1) void k_attn(
    const unsigned short* __restrict__ qT,
    const unsigned short* __restrict__ kT,
    const unsigned short* __restrict__ Fbf,
    const float* __restrict__ F,
    float* __restrict__ out) {
  __shared__ unsigned short Vt[3][256 * MT];   // 48 KB, chunk-swizzled
  __shared__ unsigned short Pb[2][64 * MT];    // 8 KB, chunk-swizzled
  __shared__ float scl[2][64];
  __shared__ float linv[64];

  const int tid = threadIdx.x;
  const int w = tid >> 6;
  const int lane = tid & 63;
  const int lo = lane & 15;
  const int hi = lane >> 4;

  // bijective XCD swizzle (256 wgs, 8 XCDs)
  const int bid = (int)blockIdx.x;
  const int swz = (bid & 7) * 32 + (bid >> 3);
  const int b = swz >> 6;
  const int n0 = (swz & 63) << 6;

  // Q fragment (B operand): col=lo -> q = n0+16w+lo, k = 8*hi+j
  const bf16x8 qfrag = *(const bf16x8*)(
      qT + ((size_t)(b << 12) + n0 + (w << 4) + lo) * 32 + (hi << 3));
  const unsigned short* kTb = kT + ((size_t)(b << 12)) * 32;
  const unsigned short* Fb = Fbf + ((size_t)b << 20);

  const int crow = lane >> 2;   // staging: row within 16-row group
  const int pch = lane & 3;     // 16B chunk position

  f32x4 acc[4][4];              // [qf][cs], rows q=16qf+4hi+r, cols c=64w+16cs+lo
#pragma unroll
  for (int i = 0; i < 4; ++i)
#pragma unroll
    for (int j = 0; j < 4; ++j) acc[i][j] = (f32x4){0.f, 0.f, 0.f, 0.f};
  float mrun = -INFINITY, lrun = 0.f;

  // prologue: stage tile 0 -> buf 0  (src chunk = pos ^ (c&3): inverse swizzle)
#pragma unroll
  for (int i = 0; i < 4; ++i) {
    int c = i * 64 + (w << 4) + crow;
    gload_lds16(Fb + (size_t)c * 4096 + ((pch ^ (c & 3)) << 3),
                &Vt[0][(i * 64 + (w << 4)) * MT]);
  }
  bf16x8 kc0 = *(const bf16x8*)(kTb + ((size_t)lo) * 32 + (hi << 3));
  bf16x8 kc1 = *(const bf16x8*)(kTb + ((size_t)(16 + lo)) * 32 + (hi << 3));

  int vb = 0, vn = 1;
  for (int t = 0; t < NIT; ++t) {
    // 1) issue stage of tile t+1 into buf vn
    if (t + 1 < NIT) {
#pragma unroll
      for (int i = 0; i < 4; ++i) {
        int c = i * 64 + (w << 4) + crow;
        gload_lds16(Fb + (size_t)c * 4096 + (size_t)(t + 1) * MT + ((pch ^ (c & 3)) << 3),
                    &Vt[vn][(i * 64 + (w << 4)) * MT]);
      }
    }
    // 2) prefetch next K fragments
    bf16x8 kn0, kn1;
    if (t + 1 < NIT) {
      kn0 = *(const bf16x8*)(kTb + ((size_t)((t + 1) * MT) + lo) * 32 + (hi << 3));
      kn1 = *(const bf16x8*)(kTb + ((size_t)((t + 1) * MT) + 16 + lo) * 32 + (hi << 3));
    }
    // 3) S^T = mfma(K, Q): lane holds q = n0+16w+lo, m = t*MT + 16mf + 4hi + r
    f32x4 z = (f32x4){0.f, 0.f, 0.f, 0.f};
    f32x4 s0 = __builtin_amdgcn_mfma_f32_16x16x32_bf16(kc0, qfrag, z, 0, 0, 0);
    f32x4 s1 = __builtin_amdgcn_mfma_f32_16x16x32_bf16(kc1, qfrag, z, 0, 0, 0);

    // 4) online softmax for this lane's q
    float tmax = fmaxf(fmaxf(fmaxf(s0[0], s0[1]), fmaxf(s0[2], s0[3])),
                       fmaxf(fmaxf(s1[0], s1[1]), fmaxf(s1[2], s1[3])));
    tmax = fmaxf(tmax, __shfl_xor(tmax, 16));
    tmax = fmaxf(tmax, __shfl_xor(tmax, 32));
    float mnew = fmaxf(mrun, tmax);
    float sc = exp2f(mrun - mnew);
    mrun = mnew;
    float p00 = exp2f(s0[0] - mnew), p01 = exp2f(s0[1] - mnew);
    float p02 = exp2f(s0[2] - mnew), p03 = exp2f(s0[3] - mnew);
    float p10 = exp2f(s1[0] - mnew), p11 = exp2f(s1[1] - mnew);
    float p12 = exp2f(s1[2] - mnew), p13 = exp2f(s1[3] - mnew);
    float rsum = p00 + p01 + p02 + p03 + p10 + p11 + p12 + p13;
    rsum += __shfl_xor(rsum, 16);
    rsum += __shfl_xor(rsum, 32);
    lrun = lrun * sc + rsum;
    if (hi == 0) scl[t & 1][(w << 4) + lo] = sc;

    // pack P, write to Pb[t&1] (swizzled): row q=16w+lo, m-local = 16mf+4hi+r
    {
      const int qr = (w << 4) + lo;
      unsigned short* base = &Pb[t & 1][qr * MT];
      int ch0 = (hi >> 1), ch1 = 2 + (hi >> 1);            // mf=0 / mf=1
      uint2v v0 = {(unsigned int)f2bf(p00) | ((unsigned int)f2bf(p01) << 16),
                   (unsigned int)f2bf(p02) | ((unsigned int)f2bf(p03) << 16)};
      uint2v v1 = {(unsigned int)f2bf(p10) | ((unsigned int)f2bf(p11) << 16),
                   (unsigned int)f2bf(p12) | ((unsigned int)f2bf(p13) << 16)};
      *(uint2v*)(base + (((ch0 ^ (qr & 3)) << 3) | ((hi & 1) << 2))) = v0;
      *(uint2v*)(base + (((ch1 ^ (qr & 3)) << 3) | ((hi & 1) << 2))) = v1;
    }

    __syncthreads();   // P/scl visible; stage(t) drained (vmcnt)

    // 5) rescale accumulators (skip when all scales == 1)
    {
      f32x4 sv[4];
      bool one = true;
#pragma unroll
      for (int qf = 0; qf < 4; ++qf) {
        sv[qf] = *(const f32x4*)&scl[t & 1][(qf << 4) + (hi << 2)];
        one = one && (sv[qf][0] == 1.f) && (sv[qf][1] == 1.f) &&
              (sv[qf][2] == 1.f) && (sv[qf][3] == 1.f);
      }
      if (!__all(one)) {
#pragma unroll
        for (int qf = 0; qf < 4; ++qf)
#pragma unroll
          for (int cs = 0; cs < 4; ++cs) acc[qf][cs] *= sv[qf];
      }
    }

    // 6) PV: O[64q x 64c-slice] += P[64q x 32m] @ V[32m x 64c-slice]
    bf16x8 pf[4], vf[4];
#pragma unroll
    for (int qf = 0; qf < 4; ++qf) {
      int qr = (qf << 4) + lo;
      pf[qf] = *(const bf16x8*)&Pb[t & 1][qr * MT + ((hi ^ (qr & 3)) << 3)];
    }
#pragma unroll
    for (int cs = 0; cs < 4; ++cs) {
      int c = (w << 6) + (cs << 4) + lo;
      vf[cs] = *(const bf16x8*)&Vt[vb][c * MT + ((hi ^ (c & 3)) << 3)];
    }
#pragma unroll
    for (int qf = 0; qf < 4; ++qf)
#pragma unroll
      for (int cs = 0; cs < 4; ++cs)
        acc[qf][cs] = __builtin_amdgcn_mfma_f32_16x16x32_bf16(pf[qf], vf[cs], acc[qf][cs], 0, 0, 0);

    kc0 = kn0; kc1 = kn1;
    vb = vn; vn = (vn == 2) ? 0 : vn + 1;
  }

  // epilogue: out = F + O * (1/l)
  if (hi == 0) linv[(w << 4) + lo] = 1.f / lrun;
  __syncthreads();
  f32x4 lv[4];
#pragma unroll
  for (int qf = 0; qf < 4; ++qf) lv[qf] = *(const f32x4*)&linv[(qf << 4) + (hi << 2)];
#pragma unroll
  for (int qf = 0; qf < 4; ++qf)
#pragma unroll
    for (int cs = 0; cs < 4; ++cs) {
      size_t idx = ((size_t)(b * 256 + (w << 6) + (cs << 4) + lo)) * 4096 +
                   n0 + (qf << 4) + (hi << 2);
      f32x4 fv = *(const f32x4*)(F + idx);
      *(f32x4*)(out + idx) = fv + acc[qf][cs] * lv[qf];
    }
}

extern "C" void kernel_launch(void* const* d_in, const int* in_sizes, int n_in,
                              void* d_out, int out_size, void* d_ws, size_t ws_size,
                              hipStream_t stream) {
  const float* F   = (const float*)d_in[0];
  const float* w1a = (const float*)d_in[1];
  const float* b1a = (const float*)d_in[2];
  const float* w1b = (const float*)d_in[3];
  const float* b1b = (const float*)d_in[4];
  const float* w2a = (const float*)d_in[5];
  const float* b2a = (const float*)d_in[6];
  const float* w2b = (const float*)d_in[7];
  const float* b2b = (const float*)d_in[8];
  float* out = (float*)d_out;

  char* ws = (char*)d_ws;
  float* w1aT = (float*)(ws);
  float* w2aT = (float*)(ws + 32768);
  unsigned short* Fbf = (unsigned short*)(ws + 65536);                       // 8 MB
  unsigned short* qT  = (unsigned short*)(ws + 65536 + 8388608);             // 1 MB
  unsigned short* kT  = (unsigned short*)(ws + 65536 + 8388608 + 1048576);   // 1 MB

  hipLaunchKernelGGL(k_wprep, dim3(32), dim3(256), 0, stream, w1a, w2a, w1aT, w2aT);
  hipLaunchKernelGGL(k_cvt, dim3(2048), dim3(256), 0, stream, F, Fbf);
  hipLaunchKernelGGL(k_qk, dim3(256), dim3(128), 0, stream,
                     F, w1aT, b1a, w1b, b1b, w2aT, b2a, w2b, b2b, qT, kT);
  hipLaunchKernelGGL(k_attn, dim3(256), dim3(256), 0, stream, qT, kT, Fbf, F, out);
}

// Round 4
// 289.230 us; speedup vs baseline: 1.1850x; 1.1850x over previous
//
#include <hip/hip_runtime.h>
#include <math.h>

typedef __attribute__((ext_vector_type(4))) float f32x4;
typedef __attribute__((ext_vector_type(8))) short bf16x8;
typedef __attribute__((ext_vector_type(2))) unsigned int uint2v;
typedef __attribute__((ext_vector_type(4))) unsigned int uint4v;

#define LOG2E 1.4426950408889634f
#define MT 32

static __device__ __forceinline__ unsigned short f2bf(float f) {
  union { float f; unsigned int i; } u; u.f = f;
  unsigned int r = u.i + 0x7fffu + ((u.i >> 16) & 1u);   // RNE
  return (unsigned short)(r >> 16);
}

typedef __attribute__((address_space(3))) unsigned int lds_u32;
typedef __attribute__((address_space(1))) unsigned int g_u32;

static __device__ __forceinline__ void gload_lds16(const unsigned short* g,
                                                   const unsigned short* l) {
  __builtin_amdgcn_global_load_lds(
      (const g_u32*)(unsigned long long)g,
      (lds_u32*)(unsigned int)(unsigned long long)l, 16, 0, 0);
}

// ---------------- kernel 0: transpose first-layer weights [32][256] -> [256][32]
__global__ __launch_bounds__(256) void k_wprep(const float* __restrict__ w1a,
                                               const float* __restrict__ w2a,
                                               float* __restrict__ w1aT,
                                               float* __restrict__ w2aT) {
  int i = blockIdx.x * 256 + threadIdx.x;
  if (i < 32 * 256) {
    int o = i >> 8, c = i & 255;
    w1aT[c * 32 + o] = w1a[i];
    w2aT[c * 32 + o] = w2a[i];
  }
}

// ---------------- kernel 1: fused q+k projections + Fbf emit
// 256 blocks x 256 thr; wave = 64-channel chunk (uniform -> s_load weights);
// LDS reduce for layer-1; o-split layer-2.
__global__ __launch_bounds__(256) void k_qk(
    const float* __restrict__ F,
    const float* __restrict__ w1aT, const float* __restrict__ b1a,
    const float* __restrict__ w1b,  const float* __restrict__ b1b,
    const float* __restrict__ w2aT, const float* __restrict__ b2a,
    const float* __restrict__ w2b,  const float* __restrict__ b2b,
    unsigned short* __restrict__ Fbf,
    unsigned short* __restrict__ qT,
    unsigned short* __restrict__ kT) {
  __shared__ float hp[4][64][33];   // 33.8 KB, stride-33 = conflict-free
  const int tid = threadIdx.x;
  const int nl = tid & 63;
  const int cs = __builtin_amdgcn_readfirstlane(tid >> 6);  // wave id, uniform
  const int strip = blockIdx.x;
  const int b = strip >> 6;
  const int n0 = (strip & 63) << 6;
  const int n = n0 + nl;

  const float* Fp = F + ((size_t)(b * 256 + cs * 64)) * 4096 + n;
  unsigned short* Fbp = Fbf + ((size_t)(b * 256 + cs * 64)) * 4096 + n;

  float hq[32], hk[32];
#pragma unroll
  for (int o = 0; o < 32; ++o) { hq[o] = 0.f; hk[o] = 0.f; }

  float fa[8], fb[8];
#pragma unroll
  for (int j = 0; j < 8; ++j) fa[j] = Fp[(size_t)j * 4096];

  for (int jj = 0; jj < 64; jj += 16) {
#pragma unroll
    for (int j = 0; j < 8; ++j) fb[j] = Fp[(size_t)(jj + 8 + j) * 4096];
#pragma unroll
    for (int j = 0; j < 8; ++j) {
      Fbp[(size_t)(jj + j) * 4096] = f2bf(fa[j]);
      const float* wq = w1aT + (cs * 64 + jj + j) * 32;
      const float* wk = w2aT + (cs * 64 + jj + j) * 32;
#pragma unroll
      for (int o = 0; o < 32; ++o) { hq[o] += wq[o] * fa[j]; hk[o] += wk[o] * fa[j]; }
    }
    if (jj + 16 < 64) {
#pragma unroll
      for (int j = 0; j < 8; ++j) fa[j] = Fp[(size_t)(jj + 16 + j) * 4096];
    }
#pragma unroll
    for (int j = 0; j < 8; ++j) {
      Fbp[(size_t)(jj + 8 + j) * 4096] = f2bf(fb[j]);
      const float* wq = w1aT + (cs * 64 + jj + 8 + j) * 32;
      const float* wk = w2aT + (cs * 64 + jj + 8 + j) * 32;
#pragma unroll
      for (int o = 0; o < 32; ++o) { hq[o] += wq[o] * fb[j]; hk[o] += wk[o] * fb[j]; }
    }
  }

  // ---- q path: reduce + layer 2
#pragma unroll
  for (int o = 0; o < 32; ++o) hp[cs][nl][o] = hq[o];
  __syncthreads();
  {
    float h[32];
#pragma unroll
    for (int o = 0; o < 32; ++o)
      h[o] = fmaxf(hp[0][nl][o] + hp[1][nl][o] + hp[2][nl][o] + hp[3][nl][o] + b1a[o], 0.f);
    unsigned int pk[4];
#pragma unroll
    for (int oo = 0; oo < 8; oo += 2) {
      float s0 = b1b[cs * 8 + oo], s1 = b1b[cs * 8 + oo + 1];
#pragma unroll
      for (int i = 0; i < 32; ++i) {
        s0 += w1b[(cs * 8 + oo) * 32 + i] * h[i];
        s1 += w1b[(cs * 8 + oo + 1) * 32 + i] * h[i];
      }
      s0 *= LOG2E; s1 *= LOG2E;
      pk[oo >> 1] = (unsigned int)f2bf(s0) | ((unsigned int)f2bf(s1) << 16);
    }
    uint4v v = {pk[0], pk[1], pk[2], pk[3]};
    *(uint4v*)(qT + ((size_t)(b * 4096 + n)) * 32 + cs * 8) = v;
  }
  __syncthreads();
  // ---- k path
#pragma unroll
  for (int o = 0; o < 32; ++o) hp[cs][nl][o] = hk[o];
  __syncthreads();
  {
    float h[32];
#pragma unroll
    for (int o = 0; o < 32; ++o)
      h[o] = fmaxf(hp[0][nl][o] + hp[1][nl][o] + hp[2][nl][o] + hp[3][nl][o] + b2a[o], 0.f);
    unsigned int pk[4];
#pragma unroll
    for (int oo = 0; oo < 8; oo += 2) {
      float s0 = b2b[cs * 8 + oo], s1 = b2b[cs * 8 + oo + 1];
#pragma unroll
      for (int i = 0; i < 32; ++i) {
        s0 += w2b[(cs * 8 + oo) * 32 + i] * h[i];
        s1 += w2b[(cs * 8 + oo + 1) * 32 + i] * h[i];
      }
      pk[oo >> 1] = (unsigned int)f2bf(s0) | ((unsigned int)f2bf(s1) << 16);
    }
    uint4v v = {pk[0], pk[1], pk[2], pk[3]};
    *(uint4v*)(kT + ((size_t)(b * 4096 + n)) * 32 + cs * 8) = v;
  }
}

// ---------------- kernel 2: flash attention, split-K over m
// grid = 256*spl, 4 waves, LDS 20.7KB -> 4 blocks/CU at spl=4.
__global__ __launch_bounds__(256, 4) void k_attn(
    const unsigned short* __restrict__ qT,
    const unsigned short* __restrict__ kT,
    const unsigned short* __restrict__ Fbf,
    const float* __restrict__ F,
    float* __restrict__ out,
    float* __restrict__ Opart,
    float* __restrict__ Mpart,
    float* __restrict__ Lpart,
    int spl, int mtiles, int direct) {
  __shared__ unsigned short Vt[256 * MT];   // 16 KB
  __shared__ unsigned short Pb[64 * MT];    // 4 KB
  __shared__ float scl[64];

  const int tid = threadIdx.x;
  const int w = tid >> 6, lane = tid & 63, lo = lane & 15, hi = lane >> 4;

  const int bid = (int)blockIdx.x;
  int g, ns;
  if (spl == 4)      { g = ((bid & 7) << 1) | (bid >> 9); ns = (bid >> 3) & 63; }
  else if (spl == 2) { g = bid & 7;                       ns = bid >> 3; }
  else               { int sz = (bid & 7) * 32 + (bid >> 3); g = sz >> 6; ns = sz & 63; }
  const int b = (spl == 4) ? (g >> 2) : ((spl == 2) ? (g >> 1) : g);
  const int s = (spl == 4) ? (g & 3) : ((spl == 2) ? (g & 1) : 0);
  const int n0 = ns << 6;
  const int mt0 = s * mtiles;

  const bf16x8 qfrag = *(const bf16x8*)(
      qT + ((size_t)(b << 12) + n0 + (w << 4) + lo) * 32 + (hi << 3));
  const unsigned short* kTb = kT + ((size_t)(b << 12)) * 32;
  const unsigned short* Fb = Fbf + ((size_t)b << 20);

  const int crow = lane >> 2, pch = lane & 3;

  f32x4 acc[4][4];
#pragma unroll
  for (int i = 0; i < 4; ++i)
#pragma unroll
    for (int j = 0; j < 4; ++j) acc[i][j] = (f32x4){0.f, 0.f, 0.f, 0.f};
  float mrun = -INFINITY, lrun = 0.f;

  // prologue: stage tile mt0, load K frags
#pragma unroll
  for (int i = 0; i < 4; ++i) {
    int c = i * 64 + (w << 4) + crow;
    gload_lds16(Fb + (size_t)c * 4096 + (mt0 << 5) + ((pch ^ (c & 3)) << 3),
                &Vt[(i * 64 + (w << 4)) * MT]);
  }
  bf16x8 kc0 = *(const bf16x8*)(kTb + ((size_t)((mt0 << 5) + lo)) * 32 + (hi << 3));
  bf16x8 kc1 = *(const bf16x8*)(kTb + ((size_t)((mt0 << 5) + 16 + lo)) * 32 + (hi << 3));

  for (int t = 0; t < mtiles; ++t) {
    // A: QK^T + softmax + Pb/scl write
    f32x4 z = (f32x4){0.f, 0.f, 0.f, 0.f};
    f32x4 s0 = __builtin_amdgcn_mfma_f32_16x16x32_bf16(kc0, qfrag, z, 0, 0, 0);
    f32x4 s1 = __builtin_amdgcn_mfma_f32_16x16x32_bf16(kc1, qfrag, z, 0, 0, 0);

    float tmax = fmaxf(fmaxf(fmaxf(s0[0], s0[1]), fmaxf(s0[2], s0[3])),
                       fmaxf(fmaxf(s1[0], s1[1]), fmaxf(s1[2], s1[3])));
    tmax = fmaxf(tmax, __shfl_xor(tmax, 16));
    tmax = fmaxf(tmax, __shfl_xor(tmax, 32));
    float mnew = fmaxf(mrun, tmax);
    float sc = exp2f(mrun - mnew);
    mrun = mnew;
    float p00 = exp2f(s0[0] - mnew), p01 = exp2f(s0[1] - mnew);
    float p02 = exp2f(s0[2] - mnew), p03 = exp2f(s0[3] - mnew);
    float p10 = exp2f(s1[0] - mnew), p11 = exp2f(s1[1] - mnew);
    float p12 = exp2f(s1[2] - mnew), p13 = exp2f(s1[3] - mnew);
    float rsum = p00 + p01 + p02 + p03 + p10 + p11 + p12 + p13;
    rsum += __shfl_xor(rsum, 16);
    rsum += __shfl_xor(rsum, 32);
    lrun = lrun * sc + rsum;
    if (hi == 0) scl[(w << 4) + lo] = sc;
    {
      const int qr = (w << 4) + lo;
      unsigned short* base = &Pb[qr * MT];
      int ch0 = (hi >> 1), ch1 = 2 + (hi >> 1);
      uint2v v0 = {(unsigned int)f2bf(p00) | ((unsigned int)f2bf(p01) << 16),
                   (unsigned int)f2bf(p02) | ((unsigned int)f2bf(p03) << 16)};
      uint2v v1 = {(unsigned int)f2bf(p10) | ((unsigned int)f2bf(p11) << 16),
                   (unsigned int)f2bf(p12) | ((unsigned int)f2bf(p13) << 16)};
      *(uint2v*)(base + (((ch0 ^ (qr & 3)) << 3) | ((hi & 1) << 2))) = v0;
      *(uint2v*)(base + (((ch1 ^ (qr & 3)) << 3) | ((hi & 1) << 2))) = v1;
    }

    __syncthreads();   // B1: Pb/scl visible, Vt(t) DMA drained

    // C: rescale + PV
    {
      f32x4 sv[4];
      bool one = true;
#pragma unroll
      for (int qf = 0; qf < 4; ++qf) {
        sv[qf] = *(const f32x4*)&scl[(qf << 4) + (hi << 2)];
        one = one && (sv[qf][0] == 1.f) && (sv[qf][1] == 1.f) &&
              (sv[qf][2] == 1.f) && (sv[qf][3] == 1.f);
      }
      if (!__all(one)) {
#pragma unroll
        for (int qf = 0; qf < 4; ++qf)
#pragma unroll
          for (int cs2 = 0; cs2 < 4; ++cs2) acc[qf][cs2] *= sv[qf];
      }
    }
    bf16x8 pf[4], vf[4];
#pragma unroll
    for (int qf = 0; qf < 4; ++qf) {
      int qr = (qf << 4) + lo;
      pf[qf] = *(const bf16x8*)&Pb[qr * MT + ((hi ^ (qr & 3)) << 3)];
    }
#pragma unroll
    for (int cs2 = 0; cs2 < 4; ++cs2) {
      int c = (w << 6) + (cs2 << 4) + lo;
      vf[cs2] = *(const bf16x8*)&Vt[c * MT + ((hi ^ (c & 3)) << 3)];
    }
    __builtin_amdgcn_s_setprio(1);
#pragma unroll
    for (int qf = 0; qf < 4; ++qf)
#pragma unroll
      for (int cs2 = 0; cs2 < 4; ++cs2)
        acc[qf][cs2] = __builtin_amdgcn_mfma_f32_16x16x32_bf16(pf[qf], vf[cs2], acc[qf][cs2], 0, 0, 0);
    __builtin_amdgcn_s_setprio(0);

    __syncthreads();   // B2: PV reads done

    // D: stage t+1 + K prefetch
    if (t + 1 < mtiles) {
      int mo = (mt0 + t + 1) << 5;
#pragma unroll
      for (int i = 0; i < 4; ++i) {
        int c = i * 64 + (w << 4) + crow;
        gload_lds16(Fb + (size_t)c * 4096 + mo + ((pch ^ (c & 3)) << 3),
                    &Vt[(i * 64 + (w << 4)) * MT]);
      }
      kc0 = *(const bf16x8*)(kTb + ((size_t)(mo + lo)) * 32 + (hi << 3));
      kc1 = *(const bf16x8*)(kTb + ((size_t)(mo + 16 + lo)) * 32 + (hi << 3));
    }
  }

  if (direct) {
    if (hi == 0) scl[(w << 4) + lo] = 1.f / lrun;
    __syncthreads();
    f32x4 lv[4];
#pragma unroll
    for (int qf = 0; qf < 4; ++qf) lv[qf] = *(const f32x4*)&scl[(qf << 4) + (hi << 2)];
#pragma unroll
    for (int qf = 0; qf < 4; ++qf)
#pragma unroll
      for (int cs2 = 0; cs2 < 4; ++cs2) {
        size_t idx = ((size_t)(b * 256 + (w << 6) + (cs2 << 4) + lo)) * 4096 +
                     n0 + (qf << 4) + (hi << 2);
        f32x4 fv = *(const f32x4*)(F + idx);
        *(f32x4*)(out + idx) = fv + acc[qf][cs2] * lv[qf];
      }
  } else {
    const int bp = (b * spl + s) * 64 + ns;
    if (hi == 0) {
      Mpart[bp * 64 + (w << 4) + lo] = mrun;
      Lpart[bp * 64 + (w << 4) + lo] = lrun;
    }
    float* Ob = Opart + (size_t)bp * 256 * 64;
#pragma unroll
    for (int qf = 0; qf < 4; ++qf)
#pragma unroll
      for (int cs2 = 0; cs2 < 4; ++cs2) {
        int c = (w << 6) + (cs2 << 4) + lo;
        *(f32x4*)(Ob + (size_t)c * 64 + (qf << 4) + (hi << 2)) = acc[qf][cs2];
      }
  }
}

// ---------------- kernel 3: combine split partials + residual
__global__ __launch_bounds__(256, 4) void k_comb(
    const float* __restrict__ F, const float* __restrict__ Opart,
    const float* __restrict__ Mpart, const float* __restrict__ Lpart,
    float* __restrict__ out, int spl) {
  __shared__ float a[4][64];
  const int cid = (int)blockIdx.x;           // 1024
  const int b = cid >> 8, ns = (cid >> 2) & 63, cq = cid & 3;
  const int tid = threadIdx.x, q = tid & 63, ci = tid >> 6;
  const int n0 = ns << 6;

  if (tid < 64) {
    float mv[4], lv[4];
    float M = -INFINITY;
#pragma unroll
    for (int s2 = 0; s2 < 4; ++s2)
      if (s2 < spl) {
        int bp = (b * spl + s2) * 64 + ns;
        mv[s2] = Mpart[bp * 64 + q];
        lv[s2] = Lpart[bp * 64 + q];
        M = fmaxf(M, mv[s2]);
      }
    float L = 0.f;
#pragma unroll
    for (int s2 = 0; s2 < 4; ++s2)
      if (s2 < spl) { mv[s2] = exp2f(mv[s2] - M); L += mv[s2] * lv[s2]; }
    float Li = 1.f / L;
#pragma unroll
    for (int s2 = 0; s2 < 4; ++s2)
      if (s2 < spl) a[s2][q] = mv[s2] * Li;
  }
  __syncthreads();
  float aq[4];
#pragma unroll
  for (int s2 = 0; s2 < 4; ++s2) aq[s2] = (s2 < spl) ? a[s2][q] : 0.f;

#pragma unroll 4
  for (int cc = 0; cc < 16; ++cc) {
    int c = (cq << 6) + (ci << 4) + cc;
    float accv = 0.f;
#pragma unroll
    for (int s2 = 0; s2 < 4; ++s2)
      if (s2 < spl)
        accv += aq[s2] * Opart[((size_t)((b * spl + s2) * 64 + ns) * 256 + c) * 64 + q];
    size_t idx = ((size_t)(b * 256 + c)) * 4096 + n0 + q;
    out[idx] = F[idx] + accv;
  }
}

extern "C" void kernel_launch(void* const* d_in, const int* in_sizes, int n_in,
                              void* d_out, int out_size, void* d_ws, size_t ws_size,
                              hipStream_t stream) {
  const float* F   = (const float*)d_in[0];
  const float* w1a = (const float*)d_in[1];
  const float* b1a = (const float*)d_in[2];
  const float* w1b = (const float*)d_in[3];
  const float* b1b = (const float*)d_in[4];
  const float* w2a = (const float*)d_in[5];
  const float* b2a = (const float*)d_in[6];
  const float* w2b = (const float*)d_in[7];
  const float* b2b = (const float*)d_in[8];
  float* out = (float*)d_out;

  char* ws = (char*)d_ws;
  float* w1aT = (float*)(ws);
  float* w2aT = (float*)(ws + 32768);
  unsigned short* qT  = (unsigned short*)(ws + 65536);
  unsigned short* kT  = (unsigned short*)(ws + 65536 + 1048576);
  unsigned short* Fbf = (unsigned short*)(ws + 65536 + 2097152);
  const size_t obase = 65536 + 2097152 + 8388608;               // 10,551,296

  int spl = 1, direct = 1;
  const size_t oSz1 = 16777216, mlSz1 = 65536;
  if (ws_size >= obase + 4 * (oSz1 + 2 * mlSz1)) { spl = 4; direct = 0; }
  else if (ws_size >= obase + 2 * (oSz1 + 2 * mlSz1)) { spl = 2; direct = 0; }

  float* Opart = (float*)(ws + obase);
  float* Mpart = (float*)(ws + obase + (size_t)spl * oSz1);
  float* Lpart = (float*)(ws + obase + (size_t)spl * oSz1 + (size_t)spl * mlSz1);

  hipLaunchKernelGGL(k_wprep, dim3(32), dim3(256), 0, stream, w1a, w2a, w1aT, w2aT);
  hipLaunchKernelGGL(k_qk, dim3(256), dim3(256), 0, stream,
                     F, w1aT, b1a, w1b, b1b, w2aT, b2a, w2b, b2b, Fbf, qT, kT);
  hipLaunchKernelGGL(k_attn, dim3(256 * spl), dim3(256), 0, stream,
                     qT, kT, Fbf, F, out, Opart, Mpart, Lpart, spl, 128 / spl, direct);
  if (!direct)
    hipLaunchKernelGGL(k_comb, dim3(1024), dim3(256), 0, stream,
                       F, Opart, Mpart, Lpart, out, spl);
}